// Round 13
// baseline (116.367 us; speedup 1.0000x reference)
//
#include <hip/hip_runtime.h>

// Green-Ampt infiltration scan. B=16384 rows x T=2048 steps. Single pass,
// producer/consumer wave split + NONTEMPORAL flush stores.
//
// Evidence ledger:
//  R1:  16B/lane cached stores -> 1.88x write amplification, 345us
//  R3:  nt SCATTERED 16B stores -> 3.56x amplification (partial-line RMW)
//  R4:  LDS transpose, full 128B lines -> 176us (~2.7 TB/s writes)
//  R5-R9: concurrency/run-length/bank/L2-set variants under CACHED stores
//         -> all null (cached-write path was the wall at ~3 TB/s)
//  R10: wave-contiguous nt stores -> 132us (~4.1 TB/s). Cache path confirmed.
//  R11: +3 dedicated store waves, raw barriers -> 120us (~4.5 TB/s).
//  R12: 6 consumer waves (2/stream) -> 106us (~5.1 TB/s). Width pays under nt.
// R13: 12 consumer waves (4/stream, row quarters). Else identical.

#define GA_MIN_INF 0.1f
#define GA_EPS 1e-6f

typedef float f4 __attribute__((ext_vector_type(4)));

constexpr int ROWS  = 64;   // rows per block (= lanes of wave 0)
constexpr int TS    = 64;   // timesteps per stage (256B per row per stream)
constexpr int PITCH = 68;   // LDS row pitch in floats (16B-aligned)

__global__ __launch_bounds__(832, 1) void ga_pc(
    const float* __restrict__ precip, const float* __restrict__ K,
    const float* __restrict__ psi, const float* __restrict__ dtheta,
    float* __restrict__ out, int B, int T) {
  __shared__ float sb[2][3][ROWS * PITCH];   // [parity][stream][row*PITCH+t]

  const int tid  = threadIdx.x;
  const int wid  = tid >> 6;
  const int lane = tid & 63;
  const int rowbase = blockIdx.x * ROWS;

  const size_t BT = (size_t)B * (size_t)T;
  const int nstage = T / TS;                 // 32
  const int nsb    = T / 32;                 // 32-step sub-batches (64)

  if (wid == 0) {
    // ---------------- producer: serial recurrence into LDS stages ----------
    const int b = rowbase + lane;
    const float Kv  = K[b];
    const float kpd = Kv * (psi[b] * dtheta[b]);
    const f4* __restrict__ pr = reinterpret_cast<const f4*>(precip + (size_t)b * T);

    float F = 0.0f;
    f4 buf[8], nxt[8];
#pragma unroll
    for (int i = 0; i < 8; ++i) buf[i] = pr[i];

    int sbc = 0;
    for (int st = 0; st < nstage; ++st) {
      const int pb = st & 1;
      float* const L0 = &sb[pb][0][lane * PITCH];
      float* const L1 = &sb[pb][1][lane * PITCH];
      float* const L2 = &sb[pb][2][lane * PITCH];
#pragma unroll
      for (int q = 0; q < 2; ++q) {          // 2 x 32 steps = TS
        if (sbc + 1 < nsb) {
#pragma unroll
          for (int i = 0; i < 8; ++i) nxt[i] = pr[(sbc + 1) * 8 + i];
        }
#pragma unroll
        for (int i = 0; i < 8; ++i) {
          const f4 p = buf[i];
          f4 a, r, c;
#pragma unroll
          for (int j = 0; j < 4; ++j) {
            float rF   = __builtin_amdgcn_rcpf(fmaxf(F, GA_EPS));
            float fcap = fmaxf(Kv + kpd * rF, GA_MIN_INF);
            float fact = fminf(p[j], fcap);
            r[j] = fmaxf(p[j] - fact, 0.0f);
            F += fact;
            a[j] = fact;
            c[j] = F;
          }
          const int t0 = q * 32 + i * 4;
          *reinterpret_cast<f4*>(L0 + t0) = a;
          *reinterpret_cast<f4*>(L1 + t0) = r;
          *reinterpret_cast<f4*>(L2 + t0) = c;
        }
#pragma unroll
        for (int i = 0; i < 8; ++i) buf[i] = nxt[i];
        ++sbc;
      }
      // LDS writes visible before consumers cross the barrier; no vmcnt drain.
      asm volatile("s_waitcnt lgkmcnt(0)" ::: "memory");
      __builtin_amdgcn_s_barrier();
    }
  } else {
    // ---------- consumers: 4 waves per stream (row quarters), nt stores ----
    const int s = (wid - 1) % 3;             // stream
    const int qh = (wid - 1) / 3;            // row quarter: 0..3
    float* const dst = out + (size_t)s * BT;
    const int fr = lane >> 4;                // 0..3 : row within quad
    const int fc = (lane & 15) * 4;          // float col 0..60

    for (int st = 0; st < nstage; ++st) {
      if (st > 0) {
        const int tb = (st - 1) * TS;
        const float* const src = &sb[(st - 1) & 1][s][0];
#pragma unroll
        for (int g = 0; g < 4; ++g) {
          const int r = qh * 16 + g * 4 + fr;
          f4 v = *reinterpret_cast<const f4*>(&src[r * PITCH + fc]);
          __builtin_nontemporal_store(
              v, reinterpret_cast<f4*>(dst + (size_t)(rowbase + r) * T + tb + fc));
        }
      }
      asm volatile("s_waitcnt lgkmcnt(0)" ::: "memory");
      __builtin_amdgcn_s_barrier();
    }
    // drain final stage (producer is done; no barrier needed)
    {
      const int tb = (nstage - 1) * TS;
      const float* const src = &sb[(nstage - 1) & 1][s][0];
#pragma unroll
      for (int g = 0; g < 4; ++g) {
        const int r = qh * 16 + g * 4 + fr;
        f4 v = *reinterpret_cast<const f4*>(&src[r * PITCH + fc]);
        __builtin_nontemporal_store(
            v, reinterpret_cast<f4*>(dst + (size_t)(rowbase + r) * T + tb + fc));
      }
    }
  }
}

// Fallback for shapes not divisible by the tiling (not hit for 16384x2048).
__global__ void ga_fallback(
    const float* __restrict__ precip, const float* __restrict__ K,
    const float* __restrict__ psi, const float* __restrict__ dtheta,
    float* __restrict__ out, int B, int T) {
  int b = blockIdx.x * blockDim.x + threadIdx.x;
  if (b >= B) return;
  const float Kv  = K[b];
  const float kpd = Kv * (psi[b] * dtheta[b]);
  const size_t BT = (size_t)B * (size_t)T;
  float F = 0.0f;
  for (int t = 0; t < T; ++t) {
    float pv   = precip[(size_t)b * T + t];
    float rF   = __builtin_amdgcn_rcpf(fmaxf(F, GA_EPS));
    float fcap = fmaxf(Kv + kpd * rF, GA_MIN_INF);
    float fact = fminf(pv, fcap);
    float ro   = fmaxf(pv - fact, 0.0f);
    F += fact;
    out[(size_t)b * T + t] = fact;
    out[BT + (size_t)b * T + t] = ro;
    out[2 * BT + (size_t)b * T + t] = F;
  }
}

extern "C" void kernel_launch(void* const* d_in, const int* in_sizes, int n_in,
                              void* d_out, int out_size, void* d_ws, size_t ws_size,
                              hipStream_t stream) {
  const float* precip = (const float*)d_in[0];
  const float* K      = (const float*)d_in[1];
  const float* psi    = (const float*)d_in[2];
  const float* dtheta = (const float*)d_in[3];
  float* out = (float*)d_out;

  const int B = in_sizes[1];            // K has B elements
  const int T = in_sizes[0] / B;        // precip is B*T

  if ((B % ROWS) == 0 && (T % TS) == 0 && ((T / 32) % 2) == 0) {
    ga_pc<<<B / ROWS, 832, 0, stream>>>(precip, K, psi, dtheta, out, B, T);
  } else {
    ga_fallback<<<(B + 63) / 64, 64, 0, stream>>>(precip, K, psi, dtheta, out, B, T);
  }
}

// Round 14
// 112.565 us; speedup vs baseline: 1.0338x; 1.0338x over previous
//
#include <hip/hip_runtime.h>

// Green-Ampt infiltration scan. B=16384 rows x T=2048 steps. Single pass,
// producer/consumer wave split + NONTEMPORAL flush stores + flag handshake.
//
// Evidence ledger:
//  R1:  16B/lane cached stores -> 1.88x write amplification, 345us
//  R3:  nt SCATTERED 16B stores -> 3.56x amplification (partial-line RMW)
//  R4:  LDS transpose, full 128B lines -> 176us (~2.7 TB/s writes)
//  R5-R9: all cached-store variants null (~3 TB/s cached-write wall)
//  R10: wave-contiguous nt stores -> 132us. Cache path confirmed.
//  R11: +3 store waves, raw barriers -> 120us.
//  R12: 6 consumer waves (2/stream)  -> 106us (~5.1 TB/s). OPTIMUM so far.
//  R13: 12 consumer waves -> 116us. Width non-monotone; in-flight bytes
//       identical (48KB/CU) across R11-R13 -> lockstep sync is the residue.
// R14: R12 store mapping, but barriers -> LDS flag handshake (monotone
// counters, relaxed LDS atomics) + 3-deep staging so consumers never wait
// on producer compute and bursts smooth across stages.

#define GA_MIN_INF 0.1f
#define GA_EPS 1e-6f

typedef float f4 __attribute__((ext_vector_type(4)));

constexpr int ROWS  = 64;   // rows per block (= lanes of wave 0)
constexpr int TS    = 64;   // timesteps per stage (256B per row per stream)
constexpr int PITCH = 68;   // LDS row pitch in floats (16B-aligned)
constexpr int DEPTH = 3;    // staging depth
constexpr int NCONS = 6;    // consumer waves

__device__ __forceinline__ void wait_ge(int* p, int v) {
  while (__hip_atomic_load(p, __ATOMIC_RELAXED, __HIP_MEMORY_SCOPE_WORKGROUP) < v)
    __builtin_amdgcn_s_sleep(1);
  asm volatile("" ::: "memory");
}

__global__ __launch_bounds__(448, 1) void ga_pc(
    const float* __restrict__ precip, const float* __restrict__ K,
    const float* __restrict__ psi, const float* __restrict__ dtheta,
    float* __restrict__ out, int B, int T) {
  __shared__ float sb[DEPTH][3][ROWS * PITCH];  // [slot][stream][row*PITCH+t]
  __shared__ int prod_stage;   // stages fully written by producer
  __shared__ int done_count;   // sum over consumers of stages consumed

  const int tid  = threadIdx.x;
  const int wid  = tid >> 6;
  const int lane = tid & 63;
  const int rowbase = blockIdx.x * ROWS;

  if (tid == 0) { prod_stage = 0; done_count = 0; }
  __syncthreads();   // one-time init fence

  const size_t BT = (size_t)B * (size_t)T;
  const int nstage = T / TS;                 // 32
  const int nsb    = T / 32;                 // 32-step sub-batches (64)

  if (wid == 0) {
    // ---------------- producer: serial recurrence into LDS stages ----------
    const int b = rowbase + lane;
    const float Kv  = K[b];
    const float kpd = Kv * (psi[b] * dtheta[b]);
    const f4* __restrict__ pr = reinterpret_cast<const f4*>(precip + (size_t)b * T);

    float F = 0.0f;
    f4 buf[8], nxt[8];
#pragma unroll
    for (int i = 0; i < 8; ++i) buf[i] = pr[i];

    int sbc = 0;
    for (int st = 0; st < nstage; ++st) {
      // slot st%DEPTH was last used by stage st-DEPTH; consumers must have
      // consumed it: done_count >= NCONS*(st-DEPTH+1). <=0 passes instantly.
      wait_ge(&done_count, NCONS * (st - DEPTH + 1));

      const int pb = st % DEPTH;
      float* const L0 = &sb[pb][0][lane * PITCH];
      float* const L1 = &sb[pb][1][lane * PITCH];
      float* const L2 = &sb[pb][2][lane * PITCH];
#pragma unroll
      for (int q = 0; q < 2; ++q) {          // 2 x 32 steps = TS
        if (sbc + 1 < nsb) {
#pragma unroll
          for (int i = 0; i < 8; ++i) nxt[i] = pr[(sbc + 1) * 8 + i];
        }
#pragma unroll
        for (int i = 0; i < 8; ++i) {
          const f4 p = buf[i];
          f4 a, r, c;
#pragma unroll
          for (int j = 0; j < 4; ++j) {
            float rF   = __builtin_amdgcn_rcpf(fmaxf(F, GA_EPS));
            float fcap = fmaxf(Kv + kpd * rF, GA_MIN_INF);
            float fact = fminf(p[j], fcap);
            r[j] = fmaxf(p[j] - fact, 0.0f);
            F += fact;
            a[j] = fact;
            c[j] = F;
          }
          const int t0 = q * 32 + i * 4;
          *reinterpret_cast<f4*>(L0 + t0) = a;
          *reinterpret_cast<f4*>(L1 + t0) = r;
          *reinterpret_cast<f4*>(L2 + t0) = c;
        }
#pragma unroll
        for (int i = 0; i < 8; ++i) buf[i] = nxt[i];
        ++sbc;
      }
      // all 64 lanes' ds_writes retired (lgkmcnt is wave-granular), then publish
      asm volatile("s_waitcnt lgkmcnt(0)" ::: "memory");
      if (lane == 0)
        __hip_atomic_store(&prod_stage, st + 1, __ATOMIC_RELAXED,
                           __HIP_MEMORY_SCOPE_WORKGROUP);
    }
  } else {
    // ------------- consumers: 2 waves per stream (row halves), nt stores ---
    const int s = (wid - 1) % 3;             // stream
    const int h = (wid - 1) / 3;             // row half: 0 -> rows 0-31, 1 -> 32-63
    float* const dst = out + (size_t)s * BT;
    const int fr = lane >> 4;                // 0..3 : row within quad
    const int fc = (lane & 15) * 4;          // float col 0..60

    for (int st = 0; st < nstage; ++st) {
      wait_ge(&prod_stage, st + 1);
      const int tb = st * TS;
      const float* const src = &sb[st % DEPTH][s][0];
      f4 v[8];
#pragma unroll
      for (int g = 0; g < 8; ++g) {
        const int r = h * 32 + g * 4 + fr;
        v[g] = *reinterpret_cast<const f4*>(&src[r * PITCH + fc]);
      }
      // reads are in registers; release the slot before draining stores
      asm volatile("s_waitcnt lgkmcnt(0)" ::: "memory");
      if (lane == 0)
        __hip_atomic_fetch_add(&done_count, 1, __ATOMIC_RELAXED,
                               __HIP_MEMORY_SCOPE_WORKGROUP);
#pragma unroll
      for (int g = 0; g < 8; ++g) {
        const int r = h * 32 + g * 4 + fr;
        __builtin_nontemporal_store(
            v[g], reinterpret_cast<f4*>(dst + (size_t)(rowbase + r) * T + tb + fc));
      }
    }
  }
}

// Fallback for shapes not divisible by the tiling (not hit for 16384x2048).
__global__ void ga_fallback(
    const float* __restrict__ precip, const float* __restrict__ K,
    const float* __restrict__ psi, const float* __restrict__ dtheta,
    float* __restrict__ out, int B, int T) {
  int b = blockIdx.x * blockDim.x + threadIdx.x;
  if (b >= B) return;
  const float Kv  = K[b];
  const float kpd = Kv * (psi[b] * dtheta[b]);
  const size_t BT = (size_t)B * (size_t)T;
  float F = 0.0f;
  for (int t = 0; t < T; ++t) {
    float pv   = precip[(size_t)b * T + t];
    float rF   = __builtin_amdgcn_rcpf(fmaxf(F, GA_EPS));
    float fcap = fmaxf(Kv + kpd * rF, GA_MIN_INF);
    float fact = fminf(pv, fcap);
    float ro   = fmaxf(pv - fact, 0.0f);
    F += fact;
    out[(size_t)b * T + t] = fact;
    out[BT + (size_t)b * T + t] = ro;
    out[2 * BT + (size_t)b * T + t] = F;
  }
}

extern "C" void kernel_launch(void* const* d_in, const int* in_sizes, int n_in,
                              void* d_out, int out_size, void* d_ws, size_t ws_size,
                              hipStream_t stream) {
  const float* precip = (const float*)d_in[0];
  const float* K      = (const float*)d_in[1];
  const float* psi    = (const float*)d_in[2];
  const float* dtheta = (const float*)d_in[3];
  float* out = (float*)d_out;

  const int B = in_sizes[1];            // K has B elements
  const int T = in_sizes[0] / B;        // precip is B*T

  if ((B % ROWS) == 0 && (T % TS) == 0 && ((T / 32) % 2) == 0) {
    ga_pc<<<B / ROWS, 448, 0, stream>>>(precip, K, psi, dtheta, out, B, T);
  } else {
    ga_fallback<<<(B + 63) / 64, 64, 0, stream>>>(precip, K, psi, dtheta, out, B, T);
  }
}